// Round 3
// baseline (1472.714 us; speedup 1.0000x reference)
//
#include <hip/hip_runtime.h>
#include <hip/hip_bf16.h>

#define IGNORE_INDEX (-100)

// Problem constants (fixed by the reference setup).
constexpr int Nrows = 8192;   // B*S
constexpr int Dk    = 2048;   // hidden
constexpr int Vv    = 32000;  // vocab

// 8-phase GEMM tiling (256x256, BK=64, 8 waves).
constexpr int BM  = 256;
constexpr int BN  = 256;
constexpr int BK  = 64;
constexpr int NKT = Dk / BK;    // 32 K-tiles
constexpr int NIT = NKT / 2;    // 16 iterations (2 K-tiles each)
constexpr int NT2  = Vv / BN;   // 125 vocab tiles
constexpr int NTP2 = 128;       // padded stride for partials (fast path)

// Fallback (fp32 reg-staged, 128x128) constants.
constexpr int FBM = 128;
constexpr int FNT  = Vv / 128;  // 250
constexpr int FNTP = 256;

typedef __attribute__((ext_vector_type(8))) short   short8;
typedef __attribute__((ext_vector_type(8))) __bf16  bf16x8;
typedef __attribute__((ext_vector_type(4))) float   f32x4;

typedef const __attribute__((address_space(1))) void* gptr_t;
typedef __attribute__((address_space(3))) void*       lptr_t;

static __device__ __forceinline__ unsigned pack_bf16x2(float x, float y) {
    __hip_bfloat162 h = __float22bfloat162_rn(make_float2(x, y));
    unsigned u;
    __builtin_memcpy(&u, &h, 4);
    return u;
}

// ---------------------------------------------------------------------------
// Kernel 0: fp32 -> bf16 cast (vectorized, 8 elems/thread/iter, grid-stride).
// ---------------------------------------------------------------------------
__global__ __launch_bounds__(256)
void lce_cast_bf16(const float* __restrict__ src, unsigned short* __restrict__ dst,
                   int n8) {
    int i = blockIdx.x * blockDim.x + threadIdx.x;
    const int stride = gridDim.x * blockDim.x;
    for (; i < n8; i += stride) {
        const float4 f0 = ((const float4*)src)[(size_t)i * 2];
        const float4 f1 = ((const float4*)src)[(size_t)i * 2 + 1];
        uint4 o = make_uint4(pack_bf16x2(f0.x, f0.y), pack_bf16x2(f0.z, f0.w),
                             pack_bf16x2(f1.x, f1.y), pack_bf16x2(f1.z, f1.w));
        ((uint4*)dst)[i] = o;
    }
}

// ---------------------------------------------------------------------------
// Kernel 1 (fast path): 256x256 8-phase bf16 GEMM-LSE.
// LDS layout: [buf][khalf][256 rows][32 cols] bf16, swizzle g ^= (row>>1)&3
// (applied on the pre-swizzled global source; linear global_load_lds dest).
// Counted vmcnt(8) at odd phases only — loads stay in flight across barriers.
// ---------------------------------------------------------------------------

// Fragment reads (8 bf16 = one ds_read_b128).
#define FRAG_A(DST, BUF, KH, MH)                                               \
    _Pragma("unroll")                                                          \
    for (int mi = 0; mi < 4; ++mi) {                                           \
        const int ra = wr * 128 + ((MH) * 4 + mi) * 16 + l15;                  \
        const int g  = l4 ^ ((ra >> 1) & 3);                                   \
        DST[mi] = __builtin_bit_cast(bf16x8,                                   \
                      *(const short8*)&As[BUF][KH][ra][g * 8]);                \
    }

#define FRAG_B(DST, BUF, KH)                                                   \
    _Pragma("unroll")                                                          \
    for (int ni = 0; ni < 4; ++ni) {                                           \
        const int rb = wc * 64 + ni * 16 + l15;                                \
        const int g  = l4 ^ ((rb >> 1) & 3);                                   \
        DST[ni] = __builtin_bit_cast(bf16x8,                                   \
                      *(const short8*)&Bs[BUF][KH][rb][g * 8]);                \
    }

// Stage one half-tile (256 rows x 32 cols bf16 = 16 KB) = 2 global_load_lds.
// Source column-granule pre-swizzled so linear LDS dest + swizzled read agree.
#define STAGE(GMAT, LBASE, RB, KT, KH)                                         \
    {                                                                          \
        const int ktc = (KT) < NKT ? (KT) : NKT - 1;                           \
        _Pragma("unroll")                                                      \
        for (int l = 0; l < 2; ++l) {                                          \
            const int gl  = l * 512 + t;                                       \
            const int row = gl >> 2;                                           \
            const int cg  = (gl & 3) ^ ((row >> 1) & 3);                       \
            const unsigned short* src =                                        \
                (GMAT) + (size_t)((RB) + row) * Dk + ktc * 64 + (KH) * 32 + cg * 8; \
            __builtin_amdgcn_global_load_lds(                                  \
                (gptr_t)src, (lptr_t)((LBASE) + (l * 512 + wid * 64) * 8),     \
                16, 0, 0);                                                     \
        }                                                                      \
    }

#define MFMA16(AF, BF, MH)                                                     \
    _Pragma("unroll")                                                          \
    for (int mi = 0; mi < 4; ++mi)                                             \
        _Pragma("unroll")                                                      \
        for (int ni = 0; ni < 4; ++ni)                                         \
            acc[(MH) * 4 + mi][ni] = __builtin_amdgcn_mfma_f32_16x16x32_bf16(  \
                AF[mi], BF[ni], acc[(MH) * 4 + mi][ni], 0, 0, 0);

#define PHASE_EVEN(BUF, KH, SGM, SLB, SRB, SKT, SKH)                           \
    FRAG_B(bfr, BUF, KH);                                                      \
    FRAG_A(afr, BUF, KH, 0);                                                   \
    STAGE(SGM, SLB, SRB, SKT, SKH);                                            \
    __builtin_amdgcn_s_barrier();                                              \
    asm volatile("s_waitcnt lgkmcnt(0)" ::: "memory");                         \
    __builtin_amdgcn_sched_barrier(0);                                         \
    __builtin_amdgcn_s_setprio(1);                                             \
    MFMA16(afr, bfr, 0);                                                       \
    __builtin_amdgcn_s_setprio(0);                                             \
    __builtin_amdgcn_s_barrier();

#define PHASE_ODD(BUF, KH, SGM, SLB, SRB, SKT, SKH)                            \
    FRAG_A(afr, BUF, KH, 1);                                                   \
    STAGE(SGM, SLB, SRB, SKT, SKH);                                            \
    __builtin_amdgcn_s_barrier();                                              \
    asm volatile("s_waitcnt lgkmcnt(0)" ::: "memory");                         \
    __builtin_amdgcn_sched_barrier(0);                                         \
    __builtin_amdgcn_s_setprio(1);                                             \
    MFMA16(afr, bfr, 1);                                                       \
    __builtin_amdgcn_s_setprio(0);                                             \
    asm volatile("s_waitcnt vmcnt(8)" ::: "memory");                           \
    __builtin_amdgcn_s_barrier();

__global__ __launch_bounds__(512, 2)
void lce_gemm_lse_8ph(const unsigned short* __restrict__ ax,
                      const unsigned short* __restrict__ bx,
                      float* __restrict__ pmax, float* __restrict__ psum) {
    __shared__ __align__(16) unsigned short As[2][2][256][32];  // 64 KB
    __shared__ __align__(16) unsigned short Bs[2][2][256][32];  // 64 KB

    const int t    = threadIdx.x;
    const int lane = t & 63;
    const int wid  = t >> 6;       // 0..7
    const int wr   = wid >> 2;     // 0..1  (128-row half)
    const int wc   = wid & 3;      // 0..3  (64-col quarter)
    const int l15  = lane & 15;
    const int l4   = lane >> 4;

    // XCD-aware bijective swizzle (grid = 4000, 4000 % 8 == 0).
    const int bid = blockIdx.x;
    const int swz = (bid & 7) * ((int)gridDim.x >> 3) + (bid >> 3);
    const int mt  = swz & 31;      // row tile (fastest -> same W panel per XCD)
    const int nt  = swz >> 5;      // vocab tile
    const int rowBase = mt * BM;
    const int colBase = nt * BN;

    f32x4 acc[8][4] = {};
    bf16x8 afr[4], bfr[4];

    // Prologue: stage tile0 (both halves) + tile1 kh0, in steady-state age order.
    STAGE(ax, &As[0][0][0][0], rowBase, 0, 0);
    STAGE(bx, &Bs[0][0][0][0], colBase, 0, 0);
    STAGE(ax, &As[0][1][0][0], rowBase, 0, 1);
    STAGE(bx, &Bs[0][1][0][0], colBase, 0, 1);
    STAGE(ax, &As[1][0][0][0], rowBase, 1, 0);
    STAGE(bx, &Bs[1][0][0][0], colBase, 1, 0);
    asm volatile("s_waitcnt vmcnt(8)" ::: "memory");
    __builtin_amdgcn_s_barrier();

    for (int j = 0; j < NIT; ++j) {
        const int kt0 = 2 * j;
        // K-tile kt0 from buf0 (phases 0-3), kt0+1 from buf1 (phases 4-7).
        PHASE_EVEN(0, 0, ax, &As[1][1][0][0], rowBase, kt0 + 1, 1)
        PHASE_ODD (0, 0, bx, &Bs[1][1][0][0], colBase, kt0 + 1, 1)
        PHASE_EVEN(0, 1, ax, &As[0][0][0][0], rowBase, kt0 + 2, 0)
        PHASE_ODD (0, 1, bx, &Bs[0][0][0][0], colBase, kt0 + 2, 0)
        PHASE_EVEN(1, 0, ax, &As[0][1][0][0], rowBase, kt0 + 2, 1)
        PHASE_ODD (1, 0, bx, &Bs[0][1][0][0], colBase, kt0 + 2, 1)
        PHASE_EVEN(1, 1, ax, &As[1][0][0][0], rowBase, kt0 + 3, 0)
        PHASE_ODD (1, 1, bx, &Bs[1][0][0][0], colBase, kt0 + 3, 0)
    }

    // Drain all outstanding loads/LDS ops before reusing LDS for reduction.
    asm volatile("s_waitcnt vmcnt(0) lgkmcnt(0)" ::: "memory");
    __builtin_amdgcn_s_barrier();

    // ---- epilogue: per-row max and sum_exp over this block's 256 columns ----
    // C/D layout (m89): col = lane&15, row = (lane>>4)*4 + reg.
    float* redmax = (float*)&As[0][0][0][0];   // [256][4]
    float* redsum = redmax + 256 * 4;          // [256][4]

    #pragma unroll
    for (int m = 0; m < 8; ++m) {
        #pragma unroll
        for (int r = 0; r < 4; ++r) {
            float v = fmaxf(fmaxf(acc[m][0][r], acc[m][1][r]),
                            fmaxf(acc[m][2][r], acc[m][3][r]));
            v = fmaxf(v, __shfl_xor(v, 1));
            v = fmaxf(v, __shfl_xor(v, 2));
            v = fmaxf(v, __shfl_xor(v, 4));
            v = fmaxf(v, __shfl_xor(v, 8));
            if (l15 == 0)
                redmax[(wr * 128 + m * 16 + l4 * 4 + r) * 4 + wc] = v;
        }
    }
    __syncthreads();

    #pragma unroll
    for (int m = 0; m < 8; ++m) {
        #pragma unroll
        for (int r = 0; r < 4; ++r) {
            const int row = wr * 128 + m * 16 + l4 * 4 + r;
            const float M = fmaxf(fmaxf(redmax[row * 4 + 0], redmax[row * 4 + 1]),
                                  fmaxf(redmax[row * 4 + 2], redmax[row * 4 + 3]));
            float s = __expf(acc[m][0][r] - M) + __expf(acc[m][1][r] - M)
                    + __expf(acc[m][2][r] - M) + __expf(acc[m][3][r] - M);
            s += __shfl_xor(s, 1);
            s += __shfl_xor(s, 2);
            s += __shfl_xor(s, 4);
            s += __shfl_xor(s, 8);
            if (l15 == 0) redsum[row * 4 + wc] = s;
        }
    }
    __syncthreads();

    if (t < 256) {
        const int row = t;
        const float M = fmaxf(fmaxf(redmax[row * 4 + 0], redmax[row * 4 + 1]),
                              fmaxf(redmax[row * 4 + 2], redmax[row * 4 + 3]));
        const float S = redsum[row * 4 + 0] + redsum[row * 4 + 1]
                      + redsum[row * 4 + 2] + redsum[row * 4 + 3];
        const size_t o = (size_t)(rowBase + row) * NTP2 + nt;
        pmax[o] = M;
        psum[o] = S;
    }
}

// ---------------------------------------------------------------------------
// Kernel 1 (fallback): fp32 reg-staged 128x128 GEMM-LSE (round-1, proven).
// Used only if ws_size cannot hold the bf16 copies.
// ---------------------------------------------------------------------------
__global__ __launch_bounds__(256, 2)
void lce_gemm_lse_f32(const float* __restrict__ hx, const float* __restrict__ wx,
                      float* __restrict__ pmax, float* __restrict__ psum) {
    __shared__ unsigned short As[FBM * BK];
    __shared__ unsigned short Bs[FBM * BK];
    __shared__ float redmax[FBM][2];
    __shared__ float redsum[FBM][2];

    const int t    = threadIdx.x;
    const int lane = t & 63;
    const int wid  = t >> 6;
    const int wrow = wid >> 1;
    const int wcol = wid & 1;
    const int l15  = lane & 15;
    const int l4   = lane >> 4;

    const int rowBase = blockIdx.x * FBM;
    const int colBase = blockIdx.y * FBM;

    f32x4 acc[4][4] = {};

    const int srow   = t >> 3;
    const int schunk = t & 7;

    for (int kt = 0; kt < Dk / BK; ++kt) {
        const int kg = kt * BK + schunk * 8;
        #pragma unroll
        for (int r = 0; r < 4; ++r) {
            const int row = srow + r * 32;
            const float* src = hx + (size_t)(rowBase + row) * Dk + kg;
            float4 f0 = *(const float4*)(src);
            float4 f1 = *(const float4*)(src + 4);
            const int off = row * BK + ((schunk ^ (row & 7)) << 3);
            *(uint4*)(&As[off]) = make_uint4(
                pack_bf16x2(f0.x, f0.y), pack_bf16x2(f0.z, f0.w),
                pack_bf16x2(f1.x, f1.y), pack_bf16x2(f1.z, f1.w));
        }
        #pragma unroll
        for (int r = 0; r < 4; ++r) {
            const int row = srow + r * 32;
            const float* src = wx + (size_t)(colBase + row) * Dk + kg;
            float4 f0 = *(const float4*)(src);
            float4 f1 = *(const float4*)(src + 4);
            const int off = row * BK + ((schunk ^ (row & 7)) << 3);
            *(uint4*)(&Bs[off]) = make_uint4(
                pack_bf16x2(f0.x, f0.y), pack_bf16x2(f0.z, f0.w),
                pack_bf16x2(f1.x, f1.y), pack_bf16x2(f1.z, f1.w));
        }
        __syncthreads();

        #pragma unroll
        for (int ks = 0; ks < 2; ++ks) {
            bf16x8 av[4], bv[4];
            const int unit = ks * 4 + l4;
            #pragma unroll
            for (int m = 0; m < 4; ++m) {
                const int row = wrow * 64 + m * 16 + l15;
                const int off = row * BK + ((unit ^ (row & 7)) << 3);
                av[m] = __builtin_bit_cast(bf16x8, *(const short8*)(&As[off]));
            }
            #pragma unroll
            for (int n = 0; n < 4; ++n) {
                const int row = wcol * 64 + n * 16 + l15;
                const int off = row * BK + ((unit ^ (row & 7)) << 3);
                bv[n] = __builtin_bit_cast(bf16x8, *(const short8*)(&Bs[off]));
            }
            #pragma unroll
            for (int m = 0; m < 4; ++m)
                #pragma unroll
                for (int n = 0; n < 4; ++n)
                    acc[m][n] = __builtin_amdgcn_mfma_f32_16x16x32_bf16(
                        av[m], bv[n], acc[m][n], 0, 0, 0);
        }
        __syncthreads();
    }

    float wmax[4][4];
    #pragma unroll
    for (int m = 0; m < 4; ++m) {
        #pragma unroll
        for (int r = 0; r < 4; ++r) {
            float v = fmaxf(fmaxf(acc[m][0][r], acc[m][1][r]),
                            fmaxf(acc[m][2][r], acc[m][3][r]));
            v = fmaxf(v, __shfl_xor(v, 1));
            v = fmaxf(v, __shfl_xor(v, 2));
            v = fmaxf(v, __shfl_xor(v, 4));
            v = fmaxf(v, __shfl_xor(v, 8));
            wmax[m][r] = v;
        }
    }
    if (l15 == 0) {
        #pragma unroll
        for (int m = 0; m < 4; ++m)
            #pragma unroll
            for (int r = 0; r < 4; ++r)
                redmax[wrow * 64 + m * 16 + l4 * 4 + r][wcol] = wmax[m][r];
    }
    __syncthreads();

    #pragma unroll
    for (int m = 0; m < 4; ++m) {
        #pragma unroll
        for (int r = 0; r < 4; ++r) {
            const int row = wrow * 64 + m * 16 + l4 * 4 + r;
            const float M = fmaxf(redmax[row][0], redmax[row][1]);
            float s = __expf(acc[m][0][r] - M) + __expf(acc[m][1][r] - M)
                    + __expf(acc[m][2][r] - M) + __expf(acc[m][3][r] - M);
            s += __shfl_xor(s, 1);
            s += __shfl_xor(s, 2);
            s += __shfl_xor(s, 4);
            s += __shfl_xor(s, 8);
            if (l15 == 0) redsum[row][wcol] = s;
        }
    }
    __syncthreads();

    if (wcol == 0 && l15 == 0) {
        #pragma unroll
        for (int m = 0; m < 4; ++m)
            #pragma unroll
            for (int r = 0; r < 4; ++r) {
                const int row = wrow * 64 + m * 16 + l4 * 4 + r;
                const float M = fmaxf(redmax[row][0], redmax[row][1]);
                const float S = redsum[row][0] + redsum[row][1];
                const size_t o = (size_t)(rowBase + row) * FNTP + blockIdx.y;
                pmax[o] = M;
                psum[o] = S;
            }
    }
}

// ---------------------------------------------------------------------------
// Kernel 2: one wave per row — combine tile partials into logsumexp, exact
// fp32 target logit, per-row nll. (ntiles/ntp are runtime args.)
// ---------------------------------------------------------------------------
__global__ __launch_bounds__(256)
void lce_combine(const float* __restrict__ hx, const float* __restrict__ wx,
                 const int* __restrict__ tgt,
                 const float* __restrict__ pmax, const float* __restrict__ psum,
                 float* __restrict__ nll, int ntiles, int ntp) {
    const int row  = (blockIdx.x * blockDim.x + threadIdx.x) >> 6;
    const int lane = threadIdx.x & 63;
    if (row >= Nrows) return;

    float m = -INFINITY, s = 0.0f;
    for (int ti = lane; ti < ntiles; ti += 64) {
        const float pm = pmax[(size_t)row * ntp + ti];
        const float ps = psum[(size_t)row * ntp + ti];
        const float nm = fmaxf(m, pm);
        s = s * __expf(m - nm) + ps * __expf(pm - nm);
        m = nm;
    }
    #pragma unroll
    for (int d = 1; d < 64; d <<= 1) {
        const float om = __shfl_xor(m, d);
        const float os = __shfl_xor(s, d);
        const float nm = fmaxf(m, om);
        s = s * __expf(m - nm) + os * __expf(om - nm);
        m = nm;
    }
    const float lse = m + __logf(s);

    const int tg = tgt[row];
    const bool valid = (tg != IGNORE_INDEX);
    const int tw = valid ? tg : 0;
    const float* hr = hx + (size_t)row * Dk;
    const float* wr = wx + (size_t)tw * Dk;
    float acc = 0.0f;
    #pragma unroll
    for (int i = 0; i < 8; ++i) {
        const int off = lane * 4 + i * 256;
        float4 a = *(const float4*)(hr + off);
        float4 b = *(const float4*)(wr + off);
        acc += a.x * b.x + a.y * b.y + a.z * b.z + a.w * b.w;
    }
    #pragma unroll
    for (int d = 1; d < 64; d <<= 1) acc += __shfl_xor(acc, d);

    if (lane == 0) nll[row] = valid ? (lse - acc) : 0.0f;
}

// ---------------------------------------------------------------------------
// Kernel 3: deterministic single-block reduction -> scalar loss.
// ---------------------------------------------------------------------------
__global__ __launch_bounds__(1024)
void lce_finalize(const float* __restrict__ nll, const int* __restrict__ tgt,
                  float* __restrict__ out) {
    __shared__ float ssum[1024];
    __shared__ float scnt[1024];
    const int t = threadIdx.x;
    float s = 0.0f, c = 0.0f;
    for (int i = t; i < Nrows; i += 1024) {
        s += nll[i];
        c += (tgt[i] != IGNORE_INDEX) ? 1.0f : 0.0f;
    }
    ssum[t] = s;
    scnt[t] = c;
    __syncthreads();
    for (int d = 512; d > 0; d >>= 1) {
        if (t < d) { ssum[t] += ssum[t + d]; scnt[t] += scnt[t + d]; }
        __syncthreads();
    }
    if (t == 0) out[0] = (scnt[0] > 0.0f) ? ssum[0] / scnt[0] : ssum[0];
}

extern "C" void kernel_launch(void* const* d_in, const int* in_sizes, int n_in,
                              void* d_out, int out_size, void* d_ws, size_t ws_size,
                              hipStream_t stream) {
    const float* hx  = (const float*)d_in[0];  // [8192, 2048] f32
    const float* wx  = (const float*)d_in[1];  // [32000, 2048] f32
    const int*   tgt = (const int*)d_in[2];    // [8192] int
    float* out = (float*)d_out;

    // Fast-path workspace layout:
    //   pmax [Nrows*NTP2 f32] | psum [Nrows*NTP2 f32] | nll [Nrows f32]
    //   | hbf [Nrows*Dk bf16] | wbf [Vv*Dk bf16]
    float* pmax = (float*)d_ws;
    float* psum = pmax + (size_t)Nrows * NTP2;
    float* nll  = psum + (size_t)Nrows * NTP2;
    unsigned short* hbf = (unsigned short*)(nll + Nrows);
    unsigned short* wbf = hbf + (size_t)Nrows * Dk;

    const size_t need = (size_t)Nrows * NTP2 * 8 + (size_t)Nrows * 4
                      + ((size_t)Nrows * Dk + (size_t)Vv * Dk) * 2;

    if (ws_size >= need) {
        lce_cast_bf16<<<2048, 256, 0, stream>>>(hx, hbf, Nrows * Dk / 8);
        lce_cast_bf16<<<2048, 256, 0, stream>>>(wx, wbf, Vv * Dk / 8);
        lce_gemm_lse_8ph<<<(Nrows / BM) * NT2, 512, 0, stream>>>(hbf, wbf, pmax, psum);
        lce_combine<<<dim3((Nrows * 64) / 256), 256, 0, stream>>>(
            hx, wx, tgt, pmax, psum, nll, NT2, NTP2);
    } else {
        // Fallback: fp32 reg-staged path with its own partial layout.
        float* fpmax = (float*)d_ws;
        float* fpsum = fpmax + (size_t)Nrows * FNTP;
        float* fnll  = fpsum + (size_t)Nrows * FNTP;
        lce_gemm_lse_f32<<<dim3(Nrows / FBM, FNT), 256, 0, stream>>>(hx, wx, fpmax, fpsum);
        lce_combine<<<dim3((Nrows * 64) / 256), 256, 0, stream>>>(
            hx, wx, tgt, fpmax, fpsum, fnll, FNT, FNTP);
        nll = fnll;
    }
    lce_finalize<<<1, 1024, 0, stream>>>(nll, tgt, out);
}

// Round 4
// 1222.719 us; speedup vs baseline: 1.2045x; 1.2045x over previous
//
#include <hip/hip_runtime.h>
#include <hip/hip_bf16.h>

#define IGNORE_INDEX (-100)

// Problem constants (fixed by the reference setup).
constexpr int Nrows = 8192;   // B*S
constexpr int Dk    = 2048;   // hidden
constexpr int Vv    = 32000;  // vocab

// 8-phase GEMM tiling (256x256, BK=64, 8 waves).
constexpr int BM  = 256;
constexpr int BN  = 256;
constexpr int BK  = 64;
constexpr int NKT = Dk / BK;    // 32 K-tiles
constexpr int NIT = NKT / 2;    // 16 iterations (2 K-tiles each)
constexpr int NT2  = Vv / BN;   // 125 vocab tiles
constexpr int NTP2 = 128;       // padded stride for partials (fast path)

// Fallback (fp32 reg-staged, 128x128) constants.
constexpr int FBM = 128;
constexpr int FNT  = Vv / 128;  // 250
constexpr int FNTP = 256;

typedef __attribute__((ext_vector_type(8))) short   short8;
typedef __attribute__((ext_vector_type(8))) __bf16  bf16x8;
typedef __attribute__((ext_vector_type(4))) float   f32x4;

typedef const __attribute__((address_space(1))) void* gptr_t;
typedef __attribute__((address_space(3))) void*       lptr_t;

static __device__ __forceinline__ unsigned pack_bf16x2(float x, float y) {
    __hip_bfloat162 h = __float22bfloat162_rn(make_float2(x, y));
    unsigned u;
    __builtin_memcpy(&u, &h, 4);
    return u;
}

// ---------------------------------------------------------------------------
// Kernel 0: fp32 -> bf16 cast (vectorized, 8 elems/thread/iter, grid-stride).
// ---------------------------------------------------------------------------
__global__ __launch_bounds__(256)
void lce_cast_bf16(const float* __restrict__ src, unsigned short* __restrict__ dst,
                   int n8) {
    int i = blockIdx.x * blockDim.x + threadIdx.x;
    const int stride = gridDim.x * blockDim.x;
    for (; i < n8; i += stride) {
        const float4 f0 = ((const float4*)src)[(size_t)i * 2];
        const float4 f1 = ((const float4*)src)[(size_t)i * 2 + 1];
        uint4 o = make_uint4(pack_bf16x2(f0.x, f0.y), pack_bf16x2(f0.z, f0.w),
                             pack_bf16x2(f1.x, f1.y), pack_bf16x2(f1.z, f1.w));
        ((uint4*)dst)[i] = o;
    }
}

// ---------------------------------------------------------------------------
// Kernel 1 (fast path): 256x256 8-phase bf16 GEMM-LSE.
// Grid = (32 mt, 125 nt), mt fastest, NO explicit XCD swizzle: with the
// default b -> XCD = b%8 round-robin, mt%8 is constant per XCD, so each
// XCD's 4 A-panels (4 MB bf16) stay L2-resident for the whole kernel.
// LDS layout: [buf][khalf][256 rows][32 cols] bf16, swizzle g ^= (row>>1)&3
// (applied on the pre-swizzled global source; linear global_load_lds dest).
// Counted vmcnt(8) at odd phases only — loads stay in flight across barriers.
// ---------------------------------------------------------------------------

// Fragment reads (8 bf16 = one ds_read_b128).
#define FRAG_A(DST, BUF, KH, MH)                                               \
    _Pragma("unroll")                                                          \
    for (int mi = 0; mi < 4; ++mi) {                                           \
        const int ra = wr * 128 + ((MH) * 4 + mi) * 16 + l15;                  \
        const int g  = l4 ^ ((ra >> 1) & 3);                                   \
        DST[mi] = __builtin_bit_cast(bf16x8,                                   \
                      *(const short8*)&As[BUF][KH][ra][g * 8]);                \
    }

#define FRAG_B(DST, BUF, KH)                                                   \
    _Pragma("unroll")                                                          \
    for (int ni = 0; ni < 4; ++ni) {                                           \
        const int rb = wc * 64 + ni * 16 + l15;                                \
        const int g  = l4 ^ ((rb >> 1) & 3);                                   \
        DST[ni] = __builtin_bit_cast(bf16x8,                                   \
                      *(const short8*)&Bs[BUF][KH][rb][g * 8]);                \
    }

// Stage one half-tile (256 rows x 32 cols bf16 = 16 KB) = 2 global_load_lds.
// Source column-granule pre-swizzled so linear LDS dest + swizzled read agree.
#define STAGE(GMAT, LBASE, RB, KT, KH)                                         \
    {                                                                          \
        const int ktc = (KT) < NKT ? (KT) : NKT - 1;                           \
        _Pragma("unroll")                                                      \
        for (int l = 0; l < 2; ++l) {                                          \
            const int gl  = l * 512 + t;                                       \
            const int row = gl >> 2;                                           \
            const int cg  = (gl & 3) ^ ((row >> 1) & 3);                       \
            const unsigned short* src =                                        \
                (GMAT) + (size_t)((RB) + row) * Dk + ktc * 64 + (KH) * 32 + cg * 8; \
            __builtin_amdgcn_global_load_lds(                                  \
                (gptr_t)src, (lptr_t)((LBASE) + (l * 512 + wid * 64) * 8),     \
                16, 0, 0);                                                     \
        }                                                                      \
    }

#define MFMA16(AF, BF, MH)                                                     \
    _Pragma("unroll")                                                          \
    for (int mi = 0; mi < 4; ++mi)                                             \
        _Pragma("unroll")                                                      \
        for (int ni = 0; ni < 4; ++ni)                                         \
            acc[(MH) * 4 + mi][ni] = __builtin_amdgcn_mfma_f32_16x16x32_bf16(  \
                AF[mi], BF[ni], acc[(MH) * 4 + mi][ni], 0, 0, 0);

#define PHASE_EVEN(BUF, KH, SGM, SLB, SRB, SKT, SKH)                           \
    FRAG_B(bfr, BUF, KH);                                                      \
    FRAG_A(afr, BUF, KH, 0);                                                   \
    STAGE(SGM, SLB, SRB, SKT, SKH);                                            \
    __builtin_amdgcn_s_barrier();                                              \
    asm volatile("s_waitcnt lgkmcnt(0)" ::: "memory");                         \
    __builtin_amdgcn_sched_barrier(0);                                         \
    __builtin_amdgcn_s_setprio(1);                                             \
    MFMA16(afr, bfr, 0);                                                       \
    __builtin_amdgcn_s_setprio(0);                                             \
    __builtin_amdgcn_s_barrier();

#define PHASE_ODD(BUF, KH, SGM, SLB, SRB, SKT, SKH)                            \
    FRAG_A(afr, BUF, KH, 1);                                                   \
    STAGE(SGM, SLB, SRB, SKT, SKH);                                            \
    __builtin_amdgcn_s_barrier();                                              \
    asm volatile("s_waitcnt lgkmcnt(0)" ::: "memory");                         \
    __builtin_amdgcn_sched_barrier(0);                                         \
    __builtin_amdgcn_s_setprio(1);                                             \
    MFMA16(afr, bfr, 1);                                                       \
    __builtin_amdgcn_s_setprio(0);                                             \
    asm volatile("s_waitcnt vmcnt(8)" ::: "memory");                           \
    __builtin_amdgcn_s_barrier();

__global__ __launch_bounds__(512, 2)
void lce_gemm_lse_8ph(const unsigned short* __restrict__ ax,
                      const unsigned short* __restrict__ bx,
                      float* __restrict__ pmax, float* __restrict__ psum) {
    __shared__ __align__(16) unsigned short As[2][2][256][32];  // 64 KB
    __shared__ __align__(16) unsigned short Bs[2][2][256][32];  // 64 KB

    const int t    = threadIdx.x;
    const int lane = t & 63;
    const int wid  = t >> 6;       // 0..7
    const int wr   = wid >> 2;     // 0..1  (128-row half)
    const int wc   = wid & 3;      // 0..3  (64-col quarter)
    const int l15  = lane & 15;
    const int l4   = lane >> 4;

    // Default dispatch mapping (NO swizzle): mt = blockIdx.x (fastest).
    // b -> XCD = b%8 round-robin => mt%8 fixed per XCD => A panels L2-pinned.
    const int mt  = blockIdx.x;    // row tile
    const int nt  = blockIdx.y;    // vocab tile
    const int rowBase = mt * BM;
    const int colBase = nt * BN;

    f32x4 acc[8][4] = {};
    bf16x8 afr[4], bfr[4];

    // Prologue: stage tile0 (both halves) + tile1 kh0, in steady-state age order.
    STAGE(ax, &As[0][0][0][0], rowBase, 0, 0);
    STAGE(bx, &Bs[0][0][0][0], colBase, 0, 0);
    STAGE(ax, &As[0][1][0][0], rowBase, 0, 1);
    STAGE(bx, &Bs[0][1][0][0], colBase, 0, 1);
    STAGE(ax, &As[1][0][0][0], rowBase, 1, 0);
    STAGE(bx, &Bs[1][0][0][0], colBase, 1, 0);
    asm volatile("s_waitcnt vmcnt(8)" ::: "memory");
    __builtin_amdgcn_s_barrier();

    for (int j = 0; j < NIT; ++j) {
        const int kt0 = 2 * j;
        // K-tile kt0 from buf0 (phases 0-3), kt0+1 from buf1 (phases 4-7).
        PHASE_EVEN(0, 0, ax, &As[1][1][0][0], rowBase, kt0 + 1, 1)
        PHASE_ODD (0, 0, bx, &Bs[1][1][0][0], colBase, kt0 + 1, 1)
        PHASE_EVEN(0, 1, ax, &As[0][0][0][0], rowBase, kt0 + 2, 0)
        PHASE_ODD (0, 1, bx, &Bs[0][0][0][0], colBase, kt0 + 2, 0)
        PHASE_EVEN(1, 0, ax, &As[0][1][0][0], rowBase, kt0 + 2, 1)
        PHASE_ODD (1, 0, bx, &Bs[0][1][0][0], colBase, kt0 + 2, 1)
        PHASE_EVEN(1, 1, ax, &As[1][0][0][0], rowBase, kt0 + 3, 0)
        PHASE_ODD (1, 1, bx, &Bs[1][0][0][0], colBase, kt0 + 3, 0)
    }

    // Drain all outstanding loads/LDS ops before reusing LDS for reduction.
    asm volatile("s_waitcnt vmcnt(0) lgkmcnt(0)" ::: "memory");
    __builtin_amdgcn_s_barrier();

    // ---- epilogue: per-row max and sum_exp over this block's 256 columns ----
    // C/D layout (m89): col = lane&15, row = (lane>>4)*4 + reg.
    float* redmax = (float*)&As[0][0][0][0];   // [256][4]
    float* redsum = redmax + 256 * 4;          // [256][4]

    #pragma unroll
    for (int m = 0; m < 8; ++m) {
        #pragma unroll
        for (int r = 0; r < 4; ++r) {
            float v = fmaxf(fmaxf(acc[m][0][r], acc[m][1][r]),
                            fmaxf(acc[m][2][r], acc[m][3][r]));
            v = fmaxf(v, __shfl_xor(v, 1));
            v = fmaxf(v, __shfl_xor(v, 2));
            v = fmaxf(v, __shfl_xor(v, 4));
            v = fmaxf(v, __shfl_xor(v, 8));
            if (l15 == 0)
                redmax[(wr * 128 + m * 16 + l4 * 4 + r) * 4 + wc] = v;
        }
    }
    __syncthreads();

    #pragma unroll
    for (int m = 0; m < 8; ++m) {
        #pragma unroll
        for (int r = 0; r < 4; ++r) {
            const int row = wr * 128 + m * 16 + l4 * 4 + r;
            const float M = fmaxf(fmaxf(redmax[row * 4 + 0], redmax[row * 4 + 1]),
                                  fmaxf(redmax[row * 4 + 2], redmax[row * 4 + 3]));
            float s = __expf(acc[m][0][r] - M) + __expf(acc[m][1][r] - M)
                    + __expf(acc[m][2][r] - M) + __expf(acc[m][3][r] - M);
            s += __shfl_xor(s, 1);
            s += __shfl_xor(s, 2);
            s += __shfl_xor(s, 4);
            s += __shfl_xor(s, 8);
            if (l15 == 0) redsum[row * 4 + wc] = s;
        }
    }
    __syncthreads();

    if (t < 256) {
        const int row = t;
        const float M = fmaxf(fmaxf(redmax[row * 4 + 0], redmax[row * 4 + 1]),
                              fmaxf(redmax[row * 4 + 2], redmax[row * 4 + 3]));
        const float S = redsum[row * 4 + 0] + redsum[row * 4 + 1]
                      + redsum[row * 4 + 2] + redsum[row * 4 + 3];
        const size_t o = (size_t)(rowBase + row) * NTP2 + nt;
        pmax[o] = M;
        psum[o] = S;
    }
}

// ---------------------------------------------------------------------------
// Kernel 1 (fallback): fp32 reg-staged 128x128 GEMM-LSE (round-1, proven).
// Used only if ws_size cannot hold the bf16 copies.
// ---------------------------------------------------------------------------
__global__ __launch_bounds__(256, 2)
void lce_gemm_lse_f32(const float* __restrict__ hx, const float* __restrict__ wx,
                      float* __restrict__ pmax, float* __restrict__ psum) {
    __shared__ unsigned short As[FBM * BK];
    __shared__ unsigned short Bs[FBM * BK];
    __shared__ float redmax[FBM][2];
    __shared__ float redsum[FBM][2];

    const int t    = threadIdx.x;
    const int lane = t & 63;
    const int wid  = t >> 6;
    const int wrow = wid >> 1;
    const int wcol = wid & 1;
    const int l15  = lane & 15;
    const int l4   = lane >> 4;

    const int rowBase = blockIdx.x * FBM;
    const int colBase = blockIdx.y * FBM;

    f32x4 acc[4][4] = {};

    const int srow   = t >> 3;
    const int schunk = t & 7;

    for (int kt = 0; kt < Dk / BK; ++kt) {
        const int kg = kt * BK + schunk * 8;
        #pragma unroll
        for (int r = 0; r < 4; ++r) {
            const int row = srow + r * 32;
            const float* src = hx + (size_t)(rowBase + row) * Dk + kg;
            float4 f0 = *(const float4*)(src);
            float4 f1 = *(const float4*)(src + 4);
            const int off = row * BK + ((schunk ^ (row & 7)) << 3);
            *(uint4*)(&As[off]) = make_uint4(
                pack_bf16x2(f0.x, f0.y), pack_bf16x2(f0.z, f0.w),
                pack_bf16x2(f1.x, f1.y), pack_bf16x2(f1.z, f1.w));
        }
        #pragma unroll
        for (int r = 0; r < 4; ++r) {
            const int row = srow + r * 32;
            const float* src = wx + (size_t)(colBase + row) * Dk + kg;
            float4 f0 = *(const float4*)(src);
            float4 f1 = *(const float4*)(src + 4);
            const int off = row * BK + ((schunk ^ (row & 7)) << 3);
            *(uint4*)(&Bs[off]) = make_uint4(
                pack_bf16x2(f0.x, f0.y), pack_bf16x2(f0.z, f0.w),
                pack_bf16x2(f1.x, f1.y), pack_bf16x2(f1.z, f1.w));
        }
        __syncthreads();

        #pragma unroll
        for (int ks = 0; ks < 2; ++ks) {
            bf16x8 av[4], bv[4];
            const int unit = ks * 4 + l4;
            #pragma unroll
            for (int m = 0; m < 4; ++m) {
                const int row = wrow * 64 + m * 16 + l15;
                const int off = row * BK + ((unit ^ (row & 7)) << 3);
                av[m] = __builtin_bit_cast(bf16x8, *(const short8*)(&As[off]));
            }
            #pragma unroll
            for (int n = 0; n < 4; ++n) {
                const int row = wcol * 64 + n * 16 + l15;
                const int off = row * BK + ((unit ^ (row & 7)) << 3);
                bv[n] = __builtin_bit_cast(bf16x8, *(const short8*)(&Bs[off]));
            }
            #pragma unroll
            for (int m = 0; m < 4; ++m)
                #pragma unroll
                for (int n = 0; n < 4; ++n)
                    acc[m][n] = __builtin_amdgcn_mfma_f32_16x16x32_bf16(
                        av[m], bv[n], acc[m][n], 0, 0, 0);
        }
        __syncthreads();
    }

    float wmax[4][4];
    #pragma unroll
    for (int m = 0; m < 4; ++m) {
        #pragma unroll
        for (int r = 0; r < 4; ++r) {
            float v = fmaxf(fmaxf(acc[m][0][r], acc[m][1][r]),
                            fmaxf(acc[m][2][r], acc[m][3][r]));
            v = fmaxf(v, __shfl_xor(v, 1));
            v = fmaxf(v, __shfl_xor(v, 2));
            v = fmaxf(v, __shfl_xor(v, 4));
            v = fmaxf(v, __shfl_xor(v, 8));
            wmax[m][r] = v;
        }
    }
    if (l15 == 0) {
        #pragma unroll
        for (int m = 0; m < 4; ++m)
            #pragma unroll
            for (int r = 0; r < 4; ++r)
                redmax[wrow * 64 + m * 16 + l4 * 4 + r][wcol] = wmax[m][r];
    }
    __syncthreads();

    #pragma unroll
    for (int m = 0; m < 4; ++m) {
        #pragma unroll
        for (int r = 0; r < 4; ++r) {
            const int row = wrow * 64 + m * 16 + l4 * 4 + r;
            const float M = fmaxf(redmax[row][0], redmax[row][1]);
            float s = __expf(acc[m][0][r] - M) + __expf(acc[m][1][r] - M)
                    + __expf(acc[m][2][r] - M) + __expf(acc[m][3][r] - M);
            s += __shfl_xor(s, 1);
            s += __shfl_xor(s, 2);
            s += __shfl_xor(s, 4);
            s += __shfl_xor(s, 8);
            if (l15 == 0) redsum[row][wcol] = s;
        }
    }
    __syncthreads();

    if (wcol == 0 && l15 == 0) {
        #pragma unroll
        for (int m = 0; m < 4; ++m)
            #pragma unroll
            for (int r = 0; r < 4; ++r) {
                const int row = wrow * 64 + m * 16 + l4 * 4 + r;
                const float M = fmaxf(redmax[row][0], redmax[row][1]);
                const float S = redsum[row][0] + redsum[row][1];
                const size_t o = (size_t)(rowBase + row) * FNTP + blockIdx.y;
                pmax[o] = M;
                psum[o] = S;
            }
    }
}

// ---------------------------------------------------------------------------
// Kernel 2: one wave per row — combine tile partials into logsumexp, exact
// fp32 target logit, per-row nll. (ntiles/ntp are runtime args.)
// ---------------------------------------------------------------------------
__global__ __launch_bounds__(256)
void lce_combine(const float* __restrict__ hx, const float* __restrict__ wx,
                 const int* __restrict__ tgt,
                 const float* __restrict__ pmax, const float* __restrict__ psum,
                 float* __restrict__ nll, int ntiles, int ntp) {
    const int row  = (blockIdx.x * blockDim.x + threadIdx.x) >> 6;
    const int lane = threadIdx.x & 63;
    if (row >= Nrows) return;

    float m = -INFINITY, s = 0.0f;
    for (int ti = lane; ti < ntiles; ti += 64) {
        const float pm = pmax[(size_t)row * ntp + ti];
        const float ps = psum[(size_t)row * ntp + ti];
        const float nm = fmaxf(m, pm);
        s = s * __expf(m - nm) + ps * __expf(pm - nm);
        m = nm;
    }
    #pragma unroll
    for (int d = 1; d < 64; d <<= 1) {
        const float om = __shfl_xor(m, d);
        const float os = __shfl_xor(s, d);
        const float nm = fmaxf(m, om);
        s = s * __expf(m - nm) + os * __expf(om - nm);
        m = nm;
    }
    const float lse = m + __logf(s);

    const int tg = tgt[row];
    const bool valid = (tg != IGNORE_INDEX);
    const int tw = valid ? tg : 0;
    const float* hr = hx + (size_t)row * Dk;
    const float* wr = wx + (size_t)tw * Dk;
    float acc = 0.0f;
    #pragma unroll
    for (int i = 0; i < 8; ++i) {
        const int off = lane * 4 + i * 256;
        float4 a = *(const float4*)(hr + off);
        float4 b = *(const float4*)(wr + off);
        acc += a.x * b.x + a.y * b.y + a.z * b.z + a.w * b.w;
    }
    #pragma unroll
    for (int d = 1; d < 64; d <<= 1) acc += __shfl_xor(acc, d);

    if (lane == 0) nll[row] = valid ? (lse - acc) : 0.0f;
}

// ---------------------------------------------------------------------------
// Kernel 3: deterministic single-block reduction -> scalar loss.
// ---------------------------------------------------------------------------
__global__ __launch_bounds__(1024)
void lce_finalize(const float* __restrict__ nll, const int* __restrict__ tgt,
                  float* __restrict__ out) {
    __shared__ float ssum[1024];
    __shared__ float scnt[1024];
    const int t = threadIdx.x;
    float s = 0.0f, c = 0.0f;
    for (int i = t; i < Nrows; i += 1024) {
        s += nll[i];
        c += (tgt[i] != IGNORE_INDEX) ? 1.0f : 0.0f;
    }
    ssum[t] = s;
    scnt[t] = c;
    __syncthreads();
    for (int d = 512; d > 0; d >>= 1) {
        if (t < d) { ssum[t] += ssum[t + d]; scnt[t] += scnt[t + d]; }
        __syncthreads();
    }
    if (t == 0) out[0] = (scnt[0] > 0.0f) ? ssum[0] / scnt[0] : ssum[0];
}

extern "C" void kernel_launch(void* const* d_in, const int* in_sizes, int n_in,
                              void* d_out, int out_size, void* d_ws, size_t ws_size,
                              hipStream_t stream) {
    const float* hx  = (const float*)d_in[0];  // [8192, 2048] f32
    const float* wx  = (const float*)d_in[1];  // [32000, 2048] f32
    const int*   tgt = (const int*)d_in[2];    // [8192] int
    float* out = (float*)d_out;

    // Fast-path workspace layout:
    //   pmax [Nrows*NTP2 f32] | psum [Nrows*NTP2 f32] | nll [Nrows f32]
    //   | hbf [Nrows*Dk bf16] | wbf [Vv*Dk bf16]
    float* pmax = (float*)d_ws;
    float* psum = pmax + (size_t)Nrows * NTP2;
    float* nll  = psum + (size_t)Nrows * NTP2;
    unsigned short* hbf = (unsigned short*)(nll + Nrows);
    unsigned short* wbf = hbf + (size_t)Nrows * Dk;

    const size_t need = (size_t)Nrows * NTP2 * 8 + (size_t)Nrows * 4
                      + ((size_t)Nrows * Dk + (size_t)Vv * Dk) * 2;

    if (ws_size >= need) {
        lce_cast_bf16<<<2048, 256, 0, stream>>>(hx, hbf, Nrows * Dk / 8);
        lce_cast_bf16<<<2048, 256, 0, stream>>>(wx, wbf, Vv * Dk / 8);
        lce_gemm_lse_8ph<<<dim3(Nrows / BM, NT2), 512, 0, stream>>>(hbf, wbf, pmax, psum);
        lce_combine<<<dim3((Nrows * 64) / 256), 256, 0, stream>>>(
            hx, wx, tgt, pmax, psum, nll, NT2, NTP2);
    } else {
        // Fallback: fp32 reg-staged path with its own partial layout.
        float* fpmax = (float*)d_ws;
        float* fpsum = fpmax + (size_t)Nrows * FNTP;
        float* fnll  = fpsum + (size_t)Nrows * FNTP;
        lce_gemm_lse_f32<<<dim3(Nrows / FBM, FNT), 256, 0, stream>>>(hx, wx, fpmax, fpsum);
        lce_combine<<<dim3((Nrows * 64) / 256), 256, 0, stream>>>(
            hx, wx, tgt, fpmax, fpsum, fnll, FNT, FNTP);
        nll = fnll;
    }
    lce_finalize<<<1, 1024, 0, stream>>>(nll, tgt, out);
}